// Round 10
// baseline (68.475 us; speedup 1.0000x reference)
//
#include <hip/hip_runtime.h>
#include <cmath>

#define NCLUST 64
#define TSTEPS 32
#define BATCH  64
#define DIM    4096
#define REFRAC 2
#define NTHA   512               // kernel A block: 8 waves
#define NPTA   8                 // neurons per thread in A: d = tid + j*512

// Raw barrier: drain LDS ops only; global stores/loads keep floating.
#define BAR() do {                                              \
    __builtin_amdgcn_sched_barrier(0);                          \
    asm volatile("s_waitcnt lgkmcnt(0)" ::: "memory");          \
    __builtin_amdgcn_s_barrier();                               \
    __builtin_amdgcn_sched_barrier(0);                          \
} while (0)

// The LIF step, shared by both kernels so spike decisions are bit-identical:
// explicit fmaf -> no contraction ambiguity between compilation contexts.
__device__ __forceinline__ float lif_step(float x, float casc, float th,
                                          float beta_s, float beta_m,
                                          float ombm, float vreset,
                                          float& v, float& is, int& r)
{
    float isv = fmaf(beta_s, is + casc, x);
    float vn  = fmaf(beta_m, v, ombm * isv);
    float vv  = (r > 0) ? vreset : vn;
    bool  spk = (vv >= th);
    v  = spk ? (vv - th) : vv;
    r  = spk ? REFRAC : ((r > 0) ? r - 1 : 0);
    is = isv;
    return spk ? 1.0f : 0.0f;
}

// ---------------- Kernel A: sequential cascade precompute ----------------
// One block (512 thr, 8 waves) per batch row; thread owns d = tid + j*512
// (cluster = tid&63 = lane for all j). Emits only cascade[t][b][*].
//
// ONE barrier per step. Triple-buffered float count slots (round-4 proof):
// step t uses slot t%3; slot (t+1)%3 is reset (benign all-thread write of 0)
// during phase 1 of step t — its previous content (step t-2's counts) was
// last read during matvec(t-2), and any wave now in phase1(t) has passed
// BAR(t-1), which orders it after every wave's matvec(t-2); its next writer
// is phase1(t+1), after BAR(t). After BAR: ALL waves compute the 64x64
// matvec from 16 broadcast float4 reads with W*gain/64 in VGPRs — lane l's
// accumulator IS its own neurons' cascade (cluster == lane), so the cascade
// never needs a second barrier or an LDS round trip.
__global__ __launch_bounds__(NTHA)
void alif_casc(const float* __restrict__ x_in,      // (T,B,D)
               const float* __restrict__ threshold, // (D)
               const float* __restrict__ bm_raw,
               const float* __restrict__ bs_raw,
               const float* __restrict__ nw,        // (NC,NC)
               const float* __restrict__ gain,      // (NC)
               float* __restrict__ gCasc)           // (T,B,NC) workspace
{
    __shared__ __align__(16) float sCnt[3][NCLUST];  // triple-buffered counts

    const int tid  = threadIdx.x;
    const int lane = tid & 63;
    const int wav  = tid >> 6;
    const int b    = blockIdx.x;

    // Per-lane W row: sigmoid(nw[lane][c]) * gain[lane]/64 (all waves use it)
    float wReg[NCLUST];
    {
        const float g = gain[lane] * (1.0f / 64.0f);
#pragma unroll
        for (int k = 0; k < 16; k++) {
            float4 w4 = *(const float4*)(nw + lane * NCLUST + 4 * k);
            wReg[4*k+0] = g / (1.0f + expf(-w4.x));
            wReg[4*k+1] = g / (1.0f + expf(-w4.y));
            wReg[4*k+2] = g / (1.0f + expf(-w4.z));
            wReg[4*k+3] = g / (1.0f + expf(-w4.w));
        }
    }
    const float beta_m = 1.0f / (1.0f + expf(-bm_raw[0]));
    const float beta_s = 1.0f / (1.0f + expf(-bs_raw[0]));
    const float ombm   = 1.0f - beta_m;
    const float vreset = -0.1f;

    float v_[NPTA], is_[NPTA], th_[NPTA];
    int   r_[NPTA];
#pragma unroll
    for (int j = 0; j < NPTA; j++) {
        v_[j] = 0.f; is_[j] = 0.f; r_[j] = 0;
        th_[j] = threshold[tid + j * NTHA];
    }

    const size_t strideT = (size_t)BATCH * DIM;
    const float* xp = x_in + (size_t)b * DIM + tid;

    float xA[NPTA], xB[NPTA];
#pragma unroll
    for (int j = 0; j < NPTA; j++) {
        xA[j] = xp[j * NTHA];
        xB[j] = xp[strideT + j * NTHA];
    }

    if (tid < 3 * NCLUST) ((float*)sCnt)[tid] = 0.f;
    __syncthreads();

    float casc = 0.f;
    int slot = 0;
    float* const gc = gCasc + (size_t)b * NCLUST + lane;

#define ASTEP(T_, XC)                                                         \
    {                                                                         \
        float cnt = 0.f;                                                      \
        _Pragma("unroll")                                                     \
        for (int j = 0; j < NPTA; j++) {                                      \
            cnt += lif_step(XC[j], casc, th_[j], beta_s, beta_m, ombm,        \
                            vreset, v_[j], is_[j], r_[j]);                    \
        }                                                                     \
        if (cnt != 0.f) atomicAdd(&sCnt[slot][lane], cnt);                    \
        const int nslot = (slot == 2) ? 0 : slot + 1;                         \
        sCnt[nslot][lane] = 0.f;      /* reset slot for step T_+1 (proof ^) */\
        if ((T_) + 2 < TSTEPS) {                                              \
            const float* xf = xp + (size_t)((T_) + 2) * strideT;              \
            _Pragma("unroll")                                                 \
            for (int j = 0; j < NPTA; j++) XC[j] = xf[j * NTHA];              \
        }                                                                     \
        BAR();                                                                \
        {                                                                     \
            float a0 = 0.f, a1 = 0.f, a2 = 0.f, a3 = 0.f;                     \
            _Pragma("unroll")                                                 \
            for (int k = 0; k < 16; k++) {                                    \
                float4 c4 = *(const float4*)&sCnt[slot][4 * k];               \
                a0 = fmaf(c4.x, wReg[4*k+0], a0);                             \
                a1 = fmaf(c4.y, wReg[4*k+1], a1);                             \
                a2 = fmaf(c4.z, wReg[4*k+2], a2);                             \
                a3 = fmaf(c4.w, wReg[4*k+3], a3);                             \
            }                                                                 \
            casc = (a0 + a1) + (a2 + a3);  /* lane == this thread's cluster */\
            if (wav == 0) gc[(size_t)(T_) * BATCH * NCLUST] = casc;           \
            slot = nslot;                                                     \
        }                                                                     \
    }

    for (int t = 0; t < TSTEPS; t += 2) {
        ASTEP(t,     xA)
        ASTEP(t + 1, xB)
    }
#undef ASTEP
}

// ---------------- Kernel B: embarrassingly-parallel replay ----------------
// 512 blocks x 256 thr, 2 neurons/thread (float2 I/O), full chip. Stages the
// row's 32x64 cascade table in LDS, then runs the identical recursion and
// streams s/v out at full-device bandwidth. Cascade registers are a SINGLE
// sequential pair — step t+1 consumes the cascade produced at step t.
__global__ __launch_bounds__(256)
void alif_replay(const float* __restrict__ x_in,      // (T,B,D)
                 const float* __restrict__ threshold, // (D)
                 const float* __restrict__ bm_raw,
                 const float* __restrict__ bs_raw,
                 const float* __restrict__ gCasc,     // (T,B,NC)
                 float* __restrict__ out_s,           // (T,B,D)
                 float* __restrict__ out_v)           // (T,B,D)
{
    __shared__ __align__(8) float sC[TSTEPS * NCLUST];   // 8 KB

    const int tid  = threadIdx.x;
    const int b    = blockIdx.x >> 3;
    const int part = blockIdx.x & 7;
    const int d0   = part * 512 + 2 * tid;
    const int c0   = d0 & 63;                            // even

    for (int i = tid; i < TSTEPS * NCLUST; i += 256)
        sC[i] = gCasc[((size_t)(i >> 6) * BATCH + b) * NCLUST + (i & 63)];

    const float beta_m = 1.0f / (1.0f + expf(-bm_raw[0]));
    const float beta_s = 1.0f / (1.0f + expf(-bs_raw[0]));
    const float ombm   = 1.0f - beta_m;
    const float vreset = -0.1f;

    const float th0 = threshold[d0];
    const float th1 = threshold[d0 + 1];
    float v0 = 0.f, is0 = 0.f, v1 = 0.f, is1 = 0.f;
    int   r0 = 0, r1 = 0;

    const size_t strideT = (size_t)BATCH * DIM;
    const float* xp = x_in  + (size_t)b * DIM + d0;
    float*       sp = out_s + (size_t)b * DIM + d0;
    float*       vp = out_v + (size_t)b * DIM + d0;

    float2 xA = *(const float2*)xp;
    float2 xB = *(const float2*)(xp + strideT);

    __syncthreads();

    float casc0 = 0.f, casc1 = 0.f;    // cascade applied at this step (from t-1)

#define BSTEP(T_, XC)                                                         \
    {                                                                         \
        float s0 = lif_step(XC.x, casc0, th0, beta_s, beta_m, ombm, vreset,   \
                            v0, is0, r0);                                     \
        float s1 = lif_step(XC.y, casc1, th1, beta_s, beta_m, ombm, vreset,   \
                            v1, is1, r1);                                     \
        *(float2*)(sp + (size_t)(T_) * strideT) = make_float2(s0, s1);        \
        *(float2*)(vp + (size_t)(T_) * strideT) = make_float2(v0, v1);        \
        if ((T_) + 2 < TSTEPS)                                                \
            XC = *(const float2*)(xp + (size_t)((T_) + 2) * strideT);         \
        float2 cn = *(const float2*)&sC[(T_) * NCLUST + c0];                  \
        casc0 = cn.x; casc1 = cn.y;   /* cascade produced at step T_ */       \
    }

    for (int t = 0; t < TSTEPS; t += 2) {
        BSTEP(t,     xA)
        BSTEP(t + 1, xB)
    }
#undef BSTEP
}

extern "C" void kernel_launch(void* const* d_in, const int* in_sizes, int n_in,
                              void* d_out, int out_size, void* d_ws, size_t ws_size,
                              hipStream_t stream) {
    const float* x  = (const float*)d_in[0];
    const float* th = (const float*)d_in[1];
    const float* bm = (const float*)d_in[2];
    const float* bs = (const float*)d_in[3];
    const float* nw = (const float*)d_in[4];
    const float* gn = (const float*)d_in[5];
    float* out_s = (float*)d_out;
    float* out_v = out_s + (size_t)TSTEPS * BATCH * DIM;

    float* gCasc = (float*)d_ws;   // (T,B,NC) f32 = 512 KB; fully rewritten by
                                   // alif_casc before alif_replay reads it (no
                                   // memset, no cross-replay state).

    hipLaunchKernelGGL(alif_casc, dim3(BATCH), dim3(NTHA), 0, stream,
                       x, th, bm, bs, nw, gn, gCasc);
    hipLaunchKernelGGL(alif_replay, dim3(BATCH * 8), dim3(256), 0, stream,
                       x, th, bm, bs, gCasc, out_s, out_v);
}